// Round 1
// baseline (792.592 us; speedup 1.0000x reference)
//
#include <hip/hip_runtime.h>
#include <hip/hip_bf16.h>

// Problem constants (fixed by setup_inputs)
constexpr int BB  = 16384;   // batch
constexpr int CH  = 16;      // children per node
constexpr int SZ  = 256;     // SIZE
constexpr int KK  = 512;     // GEMM K = 2*SIZE (mean_h | tracking_h)
constexpr int NN  = 768;     // GEMM N = 3*SIZE
constexpr int TM  = 32;      // M-tile per block

typedef float  f32x4 __attribute__((ext_vector_type(4)));
typedef short  s16x8 __attribute__((ext_vector_type(8)));

__device__ __forceinline__ unsigned short f2bf(float x) {
    unsigned u = __builtin_bit_cast(unsigned, x);
    unsigned r = u + 0x7fffu + ((u >> 16) & 1u);   // round-to-nearest-even
    return (unsigned short)(r >> 16);
}

__device__ __forceinline__ float sigmoidf_(float x) {
    return 1.0f / (1.0f + __expf(-x));
}

// ---------------------------------------------------------------------------
// Kernel 1: convert [W_iou ; W_iou_track] (512 x 768 fp32) into bf16 MFMA
// B-fragment order: Wsw[((nt*16 + ks)*64 + lane)*8 + j] = Wcat[k][n]
//   n = nt*16 + (lane&15),  k = ks*32 + (lane>>4)*8 + j
// Also zero-init fcb[256].
// ---------------------------------------------------------------------------
__global__ void wprep(const float* __restrict__ Wiou,
                      const float* __restrict__ Wtrk,
                      unsigned short* __restrict__ Wsw,
                      float* __restrict__ fcb) {
    int g = blockIdx.x * 256 + threadIdx.x;   // 0 .. 49151
    if (g < 256) fcb[g] = 0.0f;
    if (g >= 48 * 16 * 64) return;
    int lane = g & 63;
    int ksnt = g >> 6;            // nt*16 + ks
    int ks = ksnt & 15;
    int nt = ksnt >> 4;
    int n  = nt * 16 + (lane & 15);
    int k0 = ks * 32 + (lane >> 4) * 8;
    unsigned short o8[8];
#pragma unroll
    for (int j = 0; j < 8; ++j) {
        int k = k0 + j;
        float v = (k < SZ) ? Wiou[k * NN + n] : Wtrk[(k - SZ) * NN + n];
        o8[j] = f2bf(v);
    }
    *(s16x8*)(Wsw + (size_t)g * 8) = *(s16x8*)o8;
}

// ---------------------------------------------------------------------------
// Kernel 2: fc_b[j] = sum_{t=0..15} sigmoid(b_f[j] + trk0.W_f_track[:,j]
//                                           + ch_h[t].W_f[:,j]) * ch_c[t][j]
// (only segment 0 reaches the output via cs[15]; fp32 throughout)
// ---------------------------------------------------------------------------
__global__ void fc16(const float* __restrict__ children,
                     const float* __restrict__ tracking,
                     const float* __restrict__ Wf,
                     const float* __restrict__ bf,
                     const float* __restrict__ Wft,
                     float* __restrict__ fcb) {
    int t = blockIdx.x;       // 0..15
    int j = threadIdx.x;      // 0..255
    float base = bf[j];
    for (int k = 0; k < SZ; ++k) base += tracking[k] * Wft[k * SZ + j];
    const float* ch = children + (size_t)t * KK;
    float s = 0.0f;
    for (int k = 0; k < SZ; ++k) s += ch[k] * Wf[k * SZ + j];
    float f = base + s;
    atomicAdd(&fcb[j], sigmoidf_(f) * ch[SZ + j]);
}

// ---------------------------------------------------------------------------
// Kernel 3: fused segment-mean + bf16 MFMA GEMM + activation epilogue.
// Block: 256 threads (4 waves), TM=32 rows, all N=768 columns.
// LDS: A-tile in MFMA A-fragment order, 16 ksteps x 2 m16 x 64 lanes x 8 bf16.
// ---------------------------------------------------------------------------
__global__ __launch_bounds__(256, 2) void gemm_fused(
        const float* __restrict__ children,
        const float* __restrict__ tracking,
        const unsigned short* __restrict__ Wsw,
        const float* __restrict__ biou,
        const float* __restrict__ fcb,
        float* __restrict__ out) {
    __shared__ __attribute__((aligned(16))) unsigned short Asw[16 * 2 * 64 * 8]; // 32 KB

    const int tid = threadIdx.x;
    const int b0  = blockIdx.x * TM;

    // ---- Phase 1: stage A-tile (segment means | tracking_h) into LDS ----
    const f32x4* ch4 = (const f32x4*)children;   // row stride 128 f32x4
    const f32x4* tr4 = (const f32x4*)tracking;   // row stride 128 f32x4
#pragma unroll
    for (int i = 0; i < 16; ++i) {
        int task = i * 256 + tid;      // 0..4095 = m(32) x c4(128)
        int c4 = task & 127;           // float4 column in K (k = 4*c4)
        int m  = task >> 7;            // 0..31
        int b  = b0 + m;
        f32x4 v;
        if (c4 < 64) {
            // mean over 16 children rows, h-half
            const f32x4* p = ch4 + (size_t)b * (CH * 128) + c4;
            f32x4 s = p[0];
#pragma unroll
            for (int jj = 1; jj < CH; ++jj) s += p[(size_t)jj * 128];
            v = s * (1.0f / 16.0f);
        } else {
            v = tr4[(size_t)b * 128 + (c4 - 64)];
        }
        // fragment coordinates for k = 4*c4 .. 4*c4+3
        int ks   = c4 >> 3;
        int q    = (c4 >> 1) & 3;
        int j0   = (c4 & 1) * 4;
        int lane = (m & 15) | (q << 4);
        int m16  = m >> 4;
        ushort4 pk;
        pk.x = f2bf(v[0]); pk.y = f2bf(v[1]); pk.z = f2bf(v[2]); pk.w = f2bf(v[3]);
        *(ushort4*)&Asw[(((ks * 2 + m16) * 64 + lane) * 8 + j0)] = pk;
    }
    __syncthreads();

    // ---- Phase 2: MFMA GEMM + fused epilogue ----
    const int lane = tid & 63;
    const int w    = tid >> 6;     // wave 0..3
    const int m16  = w & 1;        // row group (16 rows)
    const int sh   = w >> 1;       // column half (s in {2sh, 2sh+1})
    const int l15  = lane & 15;
    const int l4   = lane >> 4;

    for (int t = 0; t < 4; ++t) {              // column triplet (64 cols of each of i/o/u)
        f32x4 acc[3][2] = {};                  // [p=i/o/u][ss]
        const s16x8* bptr[3][2];
#pragma unroll
        for (int p = 0; p < 3; ++p)
#pragma unroll
            for (int ss = 0; ss < 2; ++ss) {
                int nt = p * 16 + t * 4 + sh * 2 + ss;
                bptr[p][ss] = (const s16x8*)(Wsw + ((size_t)(nt * 16) * 64 + lane) * 8);
            }
#pragma unroll
        for (int ks = 0; ks < 16; ++ks) {
            s16x8 a = *(const s16x8*)&Asw[((ks * 2 + m16) * 64 + lane) * 8];
#pragma unroll
            for (int p = 0; p < 3; ++p)
#pragma unroll
                for (int ss = 0; ss < 2; ++ss) {
                    s16x8 bq = bptr[p][ss][(size_t)ks * 64];
                    acc[p][ss] = __builtin_amdgcn_mfma_f32_16x16x32_bf16(
                        a, bq, acc[p][ss], 0, 0, 0);
                }
        }
        // epilogue: i/o/u -> c,h -> out[b][0:256]=h, out[b][256:512]=c
#pragma unroll
        for (int ss = 0; ss < 2; ++ss) {
            int colj = t * 64 + (sh * 2 + ss) * 16 + l15;   // 0..255
            float fb = fcb[colj];
            float bi = biou[colj];
            float bo = biou[SZ + colj];
            float bu = biou[2 * SZ + colj];
#pragma unroll
            for (int r = 0; r < 4; ++r) {
                int m = m16 * 16 + l4 * 4 + r;
                int b = b0 + m;
                float vi = acc[0][ss][r] + bi;
                float vo = acc[1][ss][r] + bo;
                float vu = acc[2][ss][r] + bu;
                float i_ = sigmoidf_(vi);
                float o_ = sigmoidf_(vo);
                float u_ = 2.0f / (1.0f + __expf(-2.0f * vu)) - 1.0f;  // tanh
                float c_ = i_ * u_ + fb;
                float h_ = o_ * c_;
                size_t ob = (size_t)b * KK;
                out[ob + colj] = h_;
                out[ob + SZ + colj] = c_;
            }
        }
    }
}

// ---------------------------------------------------------------------------
extern "C" void kernel_launch(void* const* d_in, const int* in_sizes, int n_in,
                              void* d_out, int out_size, void* d_ws, size_t ws_size,
                              hipStream_t stream) {
    const float* children = (const float*)d_in[0];
    const float* tracking = (const float*)d_in[1];
    const float* Wiou     = (const float*)d_in[2];
    const float* biou     = (const float*)d_in[3];
    const float* Wf       = (const float*)d_in[4];
    const float* bf       = (const float*)d_in[5];
    const float* Wiout    = (const float*)d_in[6];
    const float* Wft      = (const float*)d_in[7];
    float* out = (float*)d_out;

    unsigned short* Wsw = (unsigned short*)d_ws;                 // 768 KB
    float* fcb = (float*)((char*)d_ws + (size_t)KK * NN * 2);    // 1 KB

    hipLaunchKernelGGL(wprep, dim3(192), dim3(256), 0, stream, Wiou, Wiout, Wsw, fcb);
    hipLaunchKernelGGL(fc16, dim3(16), dim3(256), 0, stream,
                       children, tracking, Wf, bf, Wft, fcb);
    hipLaunchKernelGGL(gemm_fused, dim3(BB / TM), dim3(256), 0, stream,
                       children, tracking, Wsw, biou, fcb, out);
}

// Round 2
// 724.996 us; speedup vs baseline: 1.0932x; 1.0932x over previous
//
#include <hip/hip_runtime.h>
#include <hip/hip_bf16.h>

constexpr int BB  = 16384;   // batch
constexpr int CH  = 16;      // children per node
constexpr int SZ  = 256;     // SIZE
constexpr int KK  = 512;     // GEMM K = 2*SIZE
constexpr int NN  = 768;     // GEMM N = 3*SIZE

typedef float  f32x4 __attribute__((ext_vector_type(4)));
typedef short  s16x8 __attribute__((ext_vector_type(8)));

__device__ __forceinline__ unsigned short f2bf(float x) {
    unsigned u = __builtin_bit_cast(unsigned, x);
    unsigned r = u + 0x7fffu + ((u >> 16) & 1u);   // RNE
    return (unsigned short)(r >> 16);
}
__device__ __forceinline__ float sigmoidf_(float x) {
    return 1.0f / (1.0f + __expf(-x));
}
__device__ __forceinline__ void gload_lds16(const unsigned short* g, unsigned short* l) {
    __builtin_amdgcn_global_load_lds(
        (const __attribute__((address_space(1))) unsigned int*)g,
        (__attribute__((address_space(3))) unsigned int*)l,
        16, 0, 0);
}

// ---------------------------------------------------------------------------
// Kernel 1: [W_iou ; W_iou_track] (512x768 fp32) -> bf16 MFMA B-fragment order
//   Wsw[((nt*16+ks)*64+lane)*8+j] = Wcat[k][n], n=nt*16+(lane&15),
//   k=ks*32+(lane>>4)*8+j.  Also zero fcb[256].
// ---------------------------------------------------------------------------
__global__ void wprep(const float* __restrict__ Wiou,
                      const float* __restrict__ Wtrk,
                      unsigned short* __restrict__ Wsw,
                      float* __restrict__ fcb) {
    int g = blockIdx.x * 256 + threadIdx.x;   // 0 .. 49151
    if (g < 256) fcb[g] = 0.0f;
    if (g >= 48 * 16 * 64) return;
    int lane = g & 63;
    int ksnt = g >> 6;
    int ks = ksnt & 15;
    int nt = ksnt >> 4;
    int n  = nt * 16 + (lane & 15);
    int k0 = ks * 32 + (lane >> 4) * 8;
    unsigned short o8[8];
#pragma unroll
    for (int j = 0; j < 8; ++j) {
        int k = k0 + j;
        float v = (k < SZ) ? Wiou[k * NN + n] : Wtrk[(k - SZ) * NN + n];
        o8[j] = f2bf(v);
    }
    *(s16x8*)(Wsw + (size_t)g * 8) = *(s16x8*)o8;
}

// ---------------------------------------------------------------------------
// Kernel 2: fc_b[j] = sum_t sigmoid(b_f[j] + trk0.Wft[:,j] + ch_h[t].Wf[:,j])
//                     * ch_c[t][j]   for t = 0..15 (only segment 0 survives)
// ---------------------------------------------------------------------------
__global__ void fc16(const float* __restrict__ children,
                     const float* __restrict__ tracking,
                     const float* __restrict__ Wf,
                     const float* __restrict__ bf,
                     const float* __restrict__ Wft,
                     float* __restrict__ fcb) {
    int t = blockIdx.x;       // 0..15
    int j = threadIdx.x;      // 0..255
    float base = bf[j];
    for (int k = 0; k < SZ; ++k) base += tracking[k] * Wft[k * SZ + j];
    const float* ch = children + (size_t)t * KK;
    float s = 0.0f;
    for (int k = 0; k < SZ; ++k) s += ch[k] * Wf[k * SZ + j];
    atomicAdd(&fcb[j], sigmoidf_(base + s) * ch[SZ + j]);
}

// ---------------------------------------------------------------------------
// Kernel 3: streaming segment-mean + bf16 A-fragment pack.
// Thread <-> (m, c4):  c4<64: mean over 16 children rows of float4 col c4;
//                      c4>=64: tracking_h float4.  Emits ushort4 (4 bf16)
// at Apack[((g16*16+ks)*64+laneF)*8+j0] matching MFMA A-operand layout.
// ---------------------------------------------------------------------------
__global__ __launch_bounds__(256) void meanpack(
        const float* __restrict__ children,
        const float* __restrict__ tracking,
        unsigned short* __restrict__ Apack) {
    int g  = blockIdx.x * 256 + threadIdx.x;   // 0 .. 16384*128-1
    int c4 = g & 127;
    int m  = g >> 7;
    const f32x4* ch4 = (const f32x4*)children;
    const f32x4* tr4 = (const f32x4*)tracking;
    f32x4 v;
    if (c4 < 64) {
        const f32x4* p = ch4 + (size_t)m * (CH * 128) + c4;
        f32x4 s = p[0];
#pragma unroll
        for (int jj = 1; jj < CH; ++jj) s += p[(size_t)jj * 128];
        v = s * 0.0625f;
    } else {
        v = tr4[(size_t)m * 128 + (c4 - 64)];
    }
    int ks = c4 >> 3;
    int q  = (c4 >> 1) & 3;
    int j0 = (c4 & 1) * 4;
    int laneF = (m & 15) | (q << 4);
    int g16   = m >> 4;
    ushort4 pk;
    pk.x = f2bf(v[0]); pk.y = f2bf(v[1]); pk.z = f2bf(v[2]); pk.w = f2bf(v[3]);
    *(ushort4*)&Apack[(((size_t)(g16 * 16 + ks) * 64 + laneF) * 8 + j0)] = pk;
}

// ---------------------------------------------------------------------------
// Kernel 4: GEMM + fused epilogue. 256 blocks x 256 thr; wave w owns 16 rows
// (g16 = blk*4+w); A-frags held in 64 VGPRs; W tiles double-buffered through
// LDS via global_load_lds(16B).
// ---------------------------------------------------------------------------
__global__ __launch_bounds__(256, 1) void gemm2(
        const unsigned short* __restrict__ Apack,
        const unsigned short* __restrict__ Wsw,
        const float* __restrict__ biou,
        const float* __restrict__ fcb,
        float* __restrict__ out) {
    __shared__ __attribute__((aligned(16))) unsigned short Bst[2][3][16 * 64 * 8]; // 96 KB

    const int tid  = threadIdx.x;
    const int lane = tid & 63;
    const int w    = tid >> 6;
    const int l15  = lane & 15;
    const int l4   = lane >> 4;
    const int g16  = blockIdx.x * 4 + w;

    // A fragments for this wave's 16 rows: 16 ksteps x 16B
    s16x8 a[16];
    const s16x8* ap = (const s16x8*)(Apack + ((size_t)g16 * 16 * 64) * 8);
#pragma unroll
    for (int ks = 0; ks < 16; ++ks) a[ks] = ap[ks * 64 + lane];

    // stage column-tile ct (3 p-tiles x 16KB) into buffer buf
    auto kick = [&](int ct, int buf) {
#pragma unroll
        for (int i = 0; i < 12; ++i) {
            int chunk = w * 12 + i;          // 0..47
            int p  = chunk >> 4;
            int ck = chunk & 15;
            const unsigned short* gsrc =
                Wsw + ((size_t)(p * 16 + ct) * 16 * 64) * 8 + ck * 512 + lane * 8;
            gload_lds16(gsrc, &Bst[buf][p][ck * 512]);
        }
    };

    kick(0, 0);
    for (int ct = 0; ct < 16; ++ct) {
        __syncthreads();                       // drains vmcnt -> tile ct landed
        if (ct < 15) kick(ct + 1, (ct + 1) & 1);
        const int buf = ct & 1;
        f32x4 acc0 = {}, acc1 = {}, acc2 = {};
#pragma unroll
        for (int ks = 0; ks < 16; ++ks) {
            s16x8 b0 = *(const s16x8*)&Bst[buf][0][(ks * 64 + lane) * 8];
            s16x8 b1 = *(const s16x8*)&Bst[buf][1][(ks * 64 + lane) * 8];
            s16x8 b2 = *(const s16x8*)&Bst[buf][2][(ks * 64 + lane) * 8];
            acc0 = __builtin_amdgcn_mfma_f32_16x16x32_bf16(a[ks], b0, acc0, 0, 0, 0);
            acc1 = __builtin_amdgcn_mfma_f32_16x16x32_bf16(a[ks], b1, acc1, 0, 0, 0);
            acc2 = __builtin_amdgcn_mfma_f32_16x16x32_bf16(a[ks], b2, acc2, 0, 0, 0);
        }
        // epilogue for columns colj = ct*16 + l15
        int colj = ct * 16 + l15;
        float fb = fcb[colj];
        float bi = biou[colj];
        float bo = biou[SZ + colj];
        float bu = biou[2 * SZ + colj];
#pragma unroll
        for (int r = 0; r < 4; ++r) {
            int m = g16 * 16 + l4 * 4 + r;
            float vi = acc0[r] + bi;
            float vo = acc1[r] + bo;
            float vu = acc2[r] + bu;
            float i_ = sigmoidf_(vi);
            float o_ = sigmoidf_(vo);
            float u_ = 2.0f / (1.0f + __expf(-2.0f * vu)) - 1.0f;  // tanh
            float c_ = i_ * u_ + fb;
            float h_ = o_ * c_;
            size_t ob = (size_t)m * KK;
            out[ob + colj]      = h_;
            out[ob + SZ + colj] = c_;
        }
    }
}

// ---------------------------------------------------------------------------
extern "C" void kernel_launch(void* const* d_in, const int* in_sizes, int n_in,
                              void* d_out, int out_size, void* d_ws, size_t ws_size,
                              hipStream_t stream) {
    const float* children = (const float*)d_in[0];
    const float* tracking = (const float*)d_in[1];
    const float* Wiou     = (const float*)d_in[2];
    const float* biou     = (const float*)d_in[3];
    const float* Wf       = (const float*)d_in[4];
    const float* bf       = (const float*)d_in[5];
    const float* Wiout    = (const float*)d_in[6];
    const float* Wft      = (const float*)d_in[7];
    float* out = (float*)d_out;

    unsigned short* Wsw   = (unsigned short*)d_ws;                       // 768 KB
    float*          fcb   = (float*)((char*)d_ws + (1 << 20));           // 1 KB @ 1MB
    unsigned short* Apack = (unsigned short*)((char*)d_ws + (2 << 20));  // 16 MB @ 2MB

    hipLaunchKernelGGL(wprep, dim3(192), dim3(256), 0, stream, Wiou, Wiout, Wsw, fcb);
    hipLaunchKernelGGL(fc16, dim3(16), dim3(256), 0, stream,
                       children, tracking, Wf, bf, Wft, fcb);
    hipLaunchKernelGGL(meanpack, dim3(BB * 128 / 256), dim3(256), 0, stream,
                       children, tracking, Apack);
    hipLaunchKernelGGL(gemm2, dim3(BB / 64), dim3(256), 0, stream,
                       Apack, Wsw, biou, fcb, out);
}